// Round 3
// baseline (743.198 us; speedup 1.0000x reference)
//
#include <hip/hip_runtime.h>
#include <hip/hip_bf16.h>

// ---------- types ----------
typedef __attribute__((ext_vector_type(8))) short     bf16x8;   // MFMA A/B frag (4 VGPRs)
typedef __attribute__((ext_vector_type(4))) float     f32x4;    // MFMA C/D frag
typedef __attribute__((ext_vector_type(4))) unsigned short ushort4_t;

// B=512, T=256, D=256, H=128, 4H=512
#define BSZ   512
#define TSZ   256
#define DSZ   256
#define HSZ   128
#define G4    512
#define OUT1  16777216  // B*T*H

// ---------- helpers ----------
__device__ inline unsigned short f2bf(float f) {
  union { float f; unsigned int u; } v; v.f = f;
  unsigned int r = (v.u + 0x7FFFu + ((v.u >> 16) & 1u)) >> 16;
  return (unsigned short)r;
}
__device__ inline float bf2f(unsigned short s) {
  union { unsigned int u; float f; } v; v.u = ((unsigned int)s) << 16;
  return v.f;
}
__device__ inline float xw_load(const float* p, long i) { return p[i]; }
__device__ inline float xw_load(const unsigned short* p, long i) { return bf2f(p[i]); }
__device__ inline void xw_store(float* p, long i, float v) { p[i] = v; }
__device__ inline void xw_store(unsigned short* p, long i, float v) { p[i] = f2bf(v); }

__device__ inline float sig_fast(float x)  { return 1.0f / (1.0f + __expf(-x)); }
__device__ inline float tanh_fast(float x) { return 1.0f - 2.0f / (__expf(2.0f * x) + 1.0f); }

// CK-style barrier: waits LDS ops only (lgkmcnt(0)); does NOT drain vmcnt,
// so in-flight global prefetch loads / output stores survive the barrier.
__device__ inline void block_sync_lds() {
  __builtin_amdgcn_s_waitcnt(0xc07f);   // lgkmcnt(0), vmcnt=63, expcnt=7
  __builtin_amdgcn_s_barrier();
}

// ---------- kernel 1: xw[B*T, 4H] = x[B*T, D] @ Wx.T + b (bf16 MFMA, fp32 acc) ----------
// Linear grid + XCD swizzle: blocks land round-robin on XCDs (bid%8). Map so the
// 8 N-tiles of one M-group are consecutive on the SAME XCD -> x tile fetched from
// HBM once, then 7x from that XCD's L2.
template <class XWT>
__global__ __launch_bounds__(256)
void gemm_xw(const float* __restrict__ x, const float* __restrict__ Wx,
             const float* __restrict__ bias, XWT* __restrict__ xw) {
  __shared__ unsigned short aF[16384];
  __shared__ unsigned short bF[16384];

  const int tid  = threadIdx.x;
  const int bid  = blockIdx.x;
  const int xcd  = bid & 7;
  const int slot = bid >> 3;
  const int nT   = slot & 7;                 // varies fastest among same-XCD blocks
  const int mT   = xcd + ((slot >> 3) << 3); // 8 consecutive same-XCD blocks share mT
  const long mBase = (long)mT * 64;
  const int  nBase = nT * 64;

  const float* aSrc = x  + mBase * DSZ;
  const float* bSrc = Wx + (long)nBase * DSZ;

#pragma unroll
  for (int i = 0; i < 16; ++i) {
    int e  = i * 1024 + tid * 4;
    int m  = e >> 8, k = e & 255;
    int c  = k >> 5, kk = k & 31;
    int lane = (m & 15) | ((kk >> 3) << 4);
    int j  = kk & 7;
    int mt = m >> 4;
    int dst = (((c << 2) + mt) * 64 + lane) * 8 + j;
    float4 va = *(const float4*)(aSrc + e);
    float4 vb = *(const float4*)(bSrc + e);
    ushort4_t pa, pb;
    pa.x = f2bf(va.x); pa.y = f2bf(va.y); pa.z = f2bf(va.z); pa.w = f2bf(va.w);
    pb.x = f2bf(vb.x); pb.y = f2bf(vb.y); pb.z = f2bf(vb.z); pb.w = f2bf(vb.w);
    *(ushort4_t*)&aF[dst] = pa;
    *(ushort4_t*)&bF[dst] = pb;
  }
  __syncthreads();

  const int w = tid >> 6, lane = tid & 63;
  f32x4 acc[4];
#pragma unroll
  for (int nt = 0; nt < 4; ++nt) acc[nt] = (f32x4){0.f, 0.f, 0.f, 0.f};

#pragma unroll
  for (int c = 0; c < 8; ++c) {
    bf16x8 av = *(const bf16x8*)&aF[(((c << 2) + w) * 64 + lane) * 8];
#pragma unroll
    for (int nt = 0; nt < 4; ++nt) {
      bf16x8 bv = *(const bf16x8*)&bF[(((c << 2) + nt) * 64 + lane) * 8];
      acc[nt] = __builtin_amdgcn_mfma_f32_16x16x32_bf16(av, bv, acc[nt], 0, 0, 0);
    }
  }

  const int colLoc = lane & 15, rowQ = lane >> 4;
#pragma unroll
  for (int nt = 0; nt < 4; ++nt) {
    int n = nBase + nt * 16 + colLoc;
    float bv = bias[n];
#pragma unroll
    for (int r = 0; r < 4; ++r) {
      long m = mBase + w * 16 + rowQ * 4 + r;
      xw_store(xw, m * (long)G4 + n, acc[nt][r] + bv);
    }
  }
}

// ---------- kernel 2: recurrent scan via MFMA ----------
// 256 blocks x 512 threads. Wh B-frags resident in VGPRs (distributed over lanes).
// Per step: h A-frags from LDS -> 16 MFMA -> in-register ifog -> bf16 h to other
// LDS buffer -> block_sync_lds (NO vmcnt drain: output stores + depth-2 xw
// prefetch stay in flight across the barrier -- the R2 fix).
template <class XWT>
__global__ __launch_bounds__(512, 2)
void lstm_rec_mfma(const XWT* __restrict__ xw, const float* __restrict__ Wh,
                   float* __restrict__ outH, float* __restrict__ outC,
                   float* __restrict__ outP) {
  __shared__ unsigned short h_lds[2 * 2048];   // [buf][c(4)][lane(64)][j(8)] bf16

  const int tid  = threadIdx.x;
  const int w    = tid >> 6;
  const int lane = tid & 63;
  const int p    = lane & 15;
  const int r16  = lane >> 4;
  const int b0   = blockIdx.x * 2;

  // Wh -> B-frags. B[n=lane&15][k=(lane>>4)*8+j], n = q*128 + w*16 + p.
  bf16x8 whF[4][4];
#pragma unroll
  for (int q = 0; q < 4; ++q) {
#pragma unroll
    for (int c = 0; c < 4; ++c) {
      const float* src = Wh + ((q * 128 + w * 16 + p) * HSZ + c * 32 + r16 * 8);
      float4 lo = *(const float4*)src;
      float4 hi = *(const float4*)(src + 4);
      bf16x8 f;
      f[0] = (short)f2bf(lo.x); f[1] = (short)f2bf(lo.y);
      f[2] = (short)f2bf(lo.z); f[3] = (short)f2bf(lo.w);
      f[4] = (short)f2bf(hi.x); f[5] = (short)f2bf(hi.y);
      f[6] = (short)f2bf(hi.z); f[7] = (short)f2bf(hi.w);
      whF[q][c] = f;
    }
  }

  for (int i = tid; i < 2 * 2048; i += 512) h_lds[i] = 0;

  float cel0 = 0.f, cel1 = 0.f, pog0 = 0.f, pog1 = 0.f;

  const long xcol  = w * 16 + p;               // lanes 16-63 duplicate lane&15
  const long xrow0 = (long)(b0 + 0) * TSZ * G4 + xcol;
  const long xrow1 = (long)(b0 + 1) * TSZ * G4 + xcol;

  // depth-2 prefetch: xv = step t, xn = step t+1
  float xv[4][2], xn[4][2];
#pragma unroll
  for (int q = 0; q < 4; ++q) {
    xv[q][0] = xw_load(xw, xrow0 + q * 128);
    xv[q][1] = xw_load(xw, xrow1 + q * 128);
    xn[q][0] = xw_load(xw, xrow0 + (long)G4 + q * 128);
    xn[q][1] = xw_load(xw, xrow1 + (long)G4 + q * 128);
  }

  __syncthreads();   // one full barrier at init is fine

  int buf = 0;
  for (int t = 0; t < TSZ; ++t) {
    bf16x8 aF[4];
#pragma unroll
    for (int c = 0; c < 4; ++c)
      aF[c] = *(const bf16x8*)&h_lds[buf * 2048 + c * 512 + lane * 8];

    // issue loads for t+2 (2 steps of slack > ~900 cyc HBM latency)
    const int tf = (t + 2 < TSZ) ? (t + 2) : (TSZ - 1);
    float xm[4][2];
#pragma unroll
    for (int q = 0; q < 4; ++q) {
      xm[q][0] = xw_load(xw, xrow0 + (long)tf * G4 + q * 128);
      xm[q][1] = xw_load(xw, xrow1 + (long)tf * G4 + q * 128);
    }

    f32x4 acc[4];
#pragma unroll
    for (int q = 0; q < 4; ++q) {
      acc[q][0] = xv[q][0];
      acc[q][1] = xv[q][1];
      acc[q][2] = 0.f;
      acc[q][3] = 0.f;
    }

#pragma unroll
    for (int q = 0; q < 4; ++q)
#pragma unroll
      for (int c = 0; c < 4; ++c)
        acc[q] = __builtin_amdgcn_mfma_f32_16x16x32_bf16(aF[c], whF[q][c], acc[q], 0, 0, 0);

    float i0 = sig_fast(acc[0][0]), i1 = sig_fast(acc[0][1]);
    float f0 = sig_fast(acc[1][0]), f1 = sig_fast(acc[1][1]);
    float o0 = 0.85f * sig_fast(acc[2][0]) + 0.15f * pog0;
    float o1 = 0.85f * sig_fast(acc[2][1]) + 0.15f * pog1;
    float g0 = tanh_fast(acc[3][0]), g1 = tanh_fast(acc[3][1]);
    cel0 = f0 * cel0 + i0 * g0;
    cel1 = f1 * cel1 + i1 * g1;
    float h0 = o0 * tanh_fast(cel0);
    float h1 = o1 * tanh_fast(cel1);
    pog0 = o0; pog1 = o1;

    const int nbuf = buf ^ 1;
    if (lane < 16) {
      const int col = w * 16 + p;
      const long o0i = ((long)(b0 + 0) * TSZ + t) * HSZ + col;
      const long o1i = ((long)(b0 + 1) * TSZ + t) * HSZ + col;
      outH[o0i] = h0;  outC[o0i] = cel0;  outP[o0i] = o0;
      outH[o1i] = h1;  outC[o1i] = cel1;  outP[o1i] = o1;
      const int c_  = col >> 5, kk = col & 31;
      const int lhi = (kk >> 3) << 4, j = kk & 7;
      h_lds[nbuf * 2048 + c_ * 512 + (0 | lhi) * 8 + j] = f2bf(h0);
      h_lds[nbuf * 2048 + c_ * 512 + (1 | lhi) * 8 + j] = f2bf(h1);
    }
    block_sync_lds();   // LDS-only wait + barrier: stores/prefetch stay in flight

    buf = nbuf;
#pragma unroll
    for (int q = 0; q < 4; ++q) {
      xv[q][0] = xn[q][0]; xv[q][1] = xn[q][1];
      xn[q][0] = xm[q][0]; xn[q][1] = xm[q][1];
    }
  }
}

// ---------- launch ----------
extern "C" void kernel_launch(void* const* d_in, const int* in_sizes, int n_in,
                              void* d_out, int out_size, void* d_ws, size_t ws_size,
                              hipStream_t stream) {
  const float* x    = (const float*)d_in[0];
  const float* Wx   = (const float*)d_in[1];
  const float* Wh   = (const float*)d_in[2];
  const float* bias = (const float*)d_in[3];

  float* outH = (float*)d_out;
  float* outC = outH + OUT1;
  float* outP = outC + OUT1;

  dim3 g1(16384), tb1(256);   // linear grid, XCD-swizzled inside the kernel
  dim3 g2(256),   tb2(512);

  const size_t xwElems = (size_t)BSZ * TSZ * G4;
  if (ws_size >= xwElems * sizeof(float)) {
    float* xwp = (float*)d_ws;
    gemm_xw<float><<<g1, tb1, 0, stream>>>(x, Wx, bias, xwp);
    lstm_rec_mfma<float><<<g2, tb2, 0, stream>>>(xwp, Wh, outH, outC, outP);
  } else {
    unsigned short* xwp = (unsigned short*)d_ws;  // bf16 fallback
    gemm_xw<unsigned short><<<g1, tb1, 0, stream>>>(x, Wx, bias, xwp);
    lstm_rec_mfma<unsigned short><<<g2, tb2, 0, stream>>>(xwp, Wh, outH, outC, outP);
  }
}